// Round 1
// baseline (1469.151 us; speedup 1.0000x reference)
//
#include <hip/hip_runtime.h>
#include <math.h>

#define Bn 2
#define Sn 2048
#define Vn 32000
#define Dn 256
#define BSn (Bn * Sn)

// ---------------------------------------------------------------------------
// Embed: X[b,s,:] = E[tok[b,s],:] + P[s,:]
// ---------------------------------------------------------------------------
__global__ __launch_bounds__(256) void k_embed(const int* __restrict__ inp,
                                               const float* __restrict__ E,
                                               const float* __restrict__ P,
                                               float* __restrict__ X) {
    int bs = blockIdx.x;          // 0..B*S-1
    int d = threadIdx.x;          // 0..255
    int tok = inp[bs];
    int s = bs % Sn;
    X[(size_t)bs * Dn + d] = E[(size_t)tok * Dn + d] + P[(size_t)s * Dn + d];
}

// ---------------------------------------------------------------------------
// GEMM C[M,N] = alpha * A[M,K] @ Bm[N,K]^T (+ R[M,N]), batched via blockIdx.z
// 64x64 tile, 256 threads, 4x4 micro-tile, BK=16
// ---------------------------------------------------------------------------
__global__ __launch_bounds__(256)
void k_gemm_abt(const float* __restrict__ A, const float* __restrict__ Bm,
                const float* __restrict__ R, float* __restrict__ C,
                int M, int N, int K, float alpha,
                long long sA, long long sB, long long sC, long long sR) {
    int zb = blockIdx.z;
    A += (long long)zb * sA;
    Bm += (long long)zb * sB;
    C += (long long)zb * sC;
    if (R) R += (long long)zb * sR;

    int bm0 = blockIdx.y * 64;
    int bn0 = blockIdx.x * 64;

    __shared__ float As[16][64];
    __shared__ float Bs[16][64];

    int tid = threadIdx.x;
    int tx = tid & 15, ty = tid >> 4;
    int lrow = tid >> 2;            // 0..63
    int lcol = (tid & 3) * 4;       // 0,4,8,12

    float acc[4][4] = {};

    for (int k0 = 0; k0 < K; k0 += 16) {
        float4 a4 = *(const float4*)(A + (long long)(bm0 + lrow) * K + k0 + lcol);
        float4 b4 = *(const float4*)(Bm + (long long)(bn0 + lrow) * K + k0 + lcol);
        As[lcol + 0][lrow] = a4.x; As[lcol + 1][lrow] = a4.y;
        As[lcol + 2][lrow] = a4.z; As[lcol + 3][lrow] = a4.w;
        Bs[lcol + 0][lrow] = b4.x; Bs[lcol + 1][lrow] = b4.y;
        Bs[lcol + 2][lrow] = b4.z; Bs[lcol + 3][lrow] = b4.w;
        __syncthreads();
#pragma unroll
        for (int kk = 0; kk < 16; ++kk) {
            float a[4], bb[4];
#pragma unroll
            for (int i = 0; i < 4; ++i) a[i] = As[kk][ty * 4 + i];
#pragma unroll
            for (int j = 0; j < 4; ++j) bb[j] = Bs[kk][tx * 4 + j];
#pragma unroll
            for (int i = 0; i < 4; ++i)
#pragma unroll
                for (int j = 0; j < 4; ++j) acc[i][j] += a[i] * bb[j];
        }
        __syncthreads();
    }

#pragma unroll
    for (int i = 0; i < 4; ++i) {
        int row = bm0 + ty * 4 + i;
#pragma unroll
        for (int j = 0; j < 4; ++j) {
            int col = bn0 + tx * 4 + j;
            float v = acc[i][j] * alpha;
            if (R) v += R[(long long)row * N + col];
            C[(long long)row * N + col] = v;
        }
    }
}

// ---------------------------------------------------------------------------
// GEMM C[M,N] = alpha * A[M,K] @ Bm[K,N] (+ R[M,N]), batched via blockIdx.z
// ---------------------------------------------------------------------------
__global__ __launch_bounds__(256)
void k_gemm_ab(const float* __restrict__ A, const float* __restrict__ Bm,
               const float* __restrict__ R, float* __restrict__ C,
               int M, int N, int K, float alpha,
               long long sA, long long sB, long long sC, long long sR) {
    int zb = blockIdx.z;
    A += (long long)zb * sA;
    Bm += (long long)zb * sB;
    C += (long long)zb * sC;
    if (R) R += (long long)zb * sR;

    int bm0 = blockIdx.y * 64;
    int bn0 = blockIdx.x * 64;

    __shared__ float As[16][64];
    __shared__ float Bs[16][64];

    int tid = threadIdx.x;
    int tx = tid & 15, ty = tid >> 4;
    int lrow = tid >> 2;            // 0..63  (A tile row)
    int lcol = (tid & 3) * 4;       // 0,4,8,12 (A tile col)
    int brow = tid >> 4;            // 0..15 (B tile row = k)
    int bcol = (tid & 15) * 4;      // 0..60 (B tile col = n)

    float acc[4][4] = {};

    for (int k0 = 0; k0 < K; k0 += 16) {
        float4 a4 = *(const float4*)(A + (long long)(bm0 + lrow) * K + k0 + lcol);
        float4 b4 = *(const float4*)(Bm + (long long)(k0 + brow) * N + bn0 + bcol);
        As[lcol + 0][lrow] = a4.x; As[lcol + 1][lrow] = a4.y;
        As[lcol + 2][lrow] = a4.z; As[lcol + 3][lrow] = a4.w;
        *(float4*)(&Bs[brow][bcol]) = b4;
        __syncthreads();
#pragma unroll
        for (int kk = 0; kk < 16; ++kk) {
            float a[4], bb[4];
#pragma unroll
            for (int i = 0; i < 4; ++i) a[i] = As[kk][ty * 4 + i];
#pragma unroll
            for (int j = 0; j < 4; ++j) bb[j] = Bs[kk][tx * 4 + j];
#pragma unroll
            for (int i = 0; i < 4; ++i)
#pragma unroll
                for (int j = 0; j < 4; ++j) acc[i][j] += a[i] * bb[j];
        }
        __syncthreads();
    }

#pragma unroll
    for (int i = 0; i < 4; ++i) {
        int row = bm0 + ty * 4 + i;
#pragma unroll
        for (int j = 0; j < 4; ++j) {
            int col = bn0 + tx * 4 + j;
            float v = acc[i][j] * alpha;
            if (R) v += R[(long long)row * N + col];
            C[(long long)row * N + col] = v;
        }
    }
}

// ---------------------------------------------------------------------------
// Causal softmax in-place over scores[b, s, :]; one block per (b,s) row.
// Masked (t > s) entries set to 0.
// ---------------------------------------------------------------------------
__global__ __launch_bounds__(256) void k_softmax(float* __restrict__ Sc) {
    int bs = blockIdx.x;
    int b = bs / Sn, s = bs % Sn;
    float* row = Sc + (long long)b * Sn * Sn + (long long)s * Sn;
    int tid = threadIdx.x;
    int n = s + 1;  // valid length (causal)

    __shared__ float red[256];

    float m = -INFINITY;
    for (int t = tid; t < n; t += 256) m = fmaxf(m, row[t]);
    red[tid] = m;
    __syncthreads();
    for (int off = 128; off > 0; off >>= 1) {
        if (tid < off) red[tid] = fmaxf(red[tid], red[tid + off]);
        __syncthreads();
    }
    m = red[0];
    __syncthreads();

    float sum = 0.0f;
    for (int t = tid; t < n; t += 256) {
        float e = expf(row[t] - m);
        row[t] = e;
        sum += e;
    }
    red[tid] = sum;
    __syncthreads();
    for (int off = 128; off > 0; off >>= 1) {
        if (tid < off) red[tid] += red[tid + off];
        __syncthreads();
    }
    float inv = 1.0f / red[0];

    for (int t = tid; t < Sn; t += 256) {
        if (t < n)
            row[t] *= inv;
        else
            row[t] = 0.0f;
    }
}

// ---------------------------------------------------------------------------
static void launch_layer(const float* Xin, float* Xout, const float* WQK,
                         const float* WOV, float* Q, float* Vo, float* Sc,
                         hipStream_t stream) {
    // Q = Xin @ WQK^T ; Vo = Xin @ WOV^T
    k_gemm_abt<<<dim3(Dn / 64, BSn / 64, 1), 256, 0, stream>>>(
        Xin, WQK, nullptr, Q, BSn, Dn, Dn, 1.0f, 0, 0, 0, 0);
    k_gemm_abt<<<dim3(Dn / 64, BSn / 64, 1), 256, 0, stream>>>(
        Xin, WOV, nullptr, Vo, BSn, Dn, Dn, 1.0f, 0, 0, 0, 0);
    // scores = 16 * Q @ Xin^T   (batched over B)
    k_gemm_abt<<<dim3(Sn / 64, Sn / 64, Bn), 256, 0, stream>>>(
        Q, Xin, nullptr, Sc, Sn, Sn, Dn, 16.0f,
        (long long)Sn * Dn, (long long)Sn * Dn, (long long)Sn * Sn, 0);
    // causal softmax in place
    k_softmax<<<Bn * Sn, 256, 0, stream>>>(Sc);
    // Xout = Sc @ Vo + Xin   (batched over B)
    k_gemm_ab<<<dim3(Dn / 64, Sn / 64, Bn), 256, 0, stream>>>(
        Sc, Vo, Xin, Xout, Sn, Dn, Sn, 1.0f,
        (long long)Sn * Sn, (long long)Sn * Dn, (long long)Sn * Dn,
        (long long)Sn * Dn);
}

extern "C" void kernel_launch(void* const* d_in, const int* in_sizes, int n_in,
                              void* d_out, int out_size, void* d_ws,
                              size_t ws_size, hipStream_t stream) {
    const int* inp = (const int*)d_in[0];
    // d_in[1] = mask (bool) — causal by construction, not read
    const float* E = (const float*)d_in[2];
    const float* P = (const float*)d_in[3];
    const float* WQK1 = (const float*)d_in[4];
    const float* WOV1 = (const float*)d_in[5];
    const float* WQK2 = (const float*)d_in[6];
    const float* WOV2 = (const float*)d_in[7];
    const float* WF = (const float*)d_in[8];
    const float* U = (const float*)d_in[9];
    float* out = (float*)d_out;

    float* ws = (float*)d_ws;
    float* xA = ws;                              // BS*D
    float* xB = xA + (size_t)BSn * Dn;           // BS*D
    float* Q = xB + (size_t)BSn * Dn;            // BS*D
    float* Vo = Q + (size_t)BSn * Dn;            // BS*D
    float* Sc = Vo + (size_t)BSn * Dn;           // B*S*S

    // X = E[input] + P
    k_embed<<<BSn, 256, 0, stream>>>(inp, E, P, xA);

    // two attention blocks (ping-pong xA <-> xB)
    launch_layer(xA, xB, WQK1, WOV1, Q, Vo, Sc, stream);
    launch_layer(xB, xA, WQK2, WOV2, Q, Vo, Sc, stream);

    // FFN residual: xB = xA + xA @ WF^T
    k_gemm_abt<<<dim3(Dn / 64, BSn / 64, 1), 256, 0, stream>>>(
        xA, WF, xA, xB, BSn, Dn, Dn, 1.0f, 0, 0, 0, 0);

    // logits = xB @ U^T  -> d_out
    k_gemm_abt<<<dim3(Vn / 64, BSn / 64, 1), 256, 0, stream>>>(
        xB, U, nullptr, out, BSn, Vn, Dn, 1.0f, 0, 0, 0, 0);
}

// Round 2
// 417.256 us; speedup vs baseline: 3.5210x; 3.5210x over previous
//
#include <hip/hip_runtime.h>
#include <hip/hip_bf16.h>
#include <math.h>

#define Bn 2
#define Sn 2048
#define Vn 32000
#define Dn 256
#define BSn (Bn * Sn)

typedef unsigned short ushort_t;
typedef __attribute__((ext_vector_type(8))) __bf16 bf16x8;
typedef __attribute__((ext_vector_type(4))) float f32x4;
typedef __attribute__((ext_vector_type(8))) unsigned short u16x8;
typedef __attribute__((ext_vector_type(4))) unsigned short u16x4;

__device__ __forceinline__ unsigned short f2b(float v) {
    union { __bf16 b; unsigned short u; } c;
    c.b = (__bf16)v;
    return c.u;
}

// ---------------------------------------------------------------------------
// Embed: Xf[b,s,:] = E[tok[b,s],:] + P[s,:] (f32), Xb = bf16(Xf)
// ---------------------------------------------------------------------------
__global__ __launch_bounds__(256) void k_embed(const int* __restrict__ inp,
                                               const float* __restrict__ E,
                                               const float* __restrict__ P,
                                               float* __restrict__ Xf,
                                               ushort_t* __restrict__ Xb) {
    int bs = blockIdx.x;
    int d = threadIdx.x;
    int tok = inp[bs];
    int s = bs % Sn;
    float v = E[(size_t)tok * Dn + d] + P[(size_t)s * Dn + d];
    Xf[(size_t)bs * Dn + d] = v;
    Xb[(size_t)bs * Dn + d] = f2b(v);
}

// ---------------------------------------------------------------------------
// f32 -> bf16 convert (n multiple of 4)
// ---------------------------------------------------------------------------
__global__ __launch_bounds__(256) void k_convert(const float* __restrict__ in,
                                                 ushort_t* __restrict__ out,
                                                 int n) {
    int i = (blockIdx.x * 256 + threadIdx.x) * 4;
    if (i < n) {
        float4 v = *(const float4*)&in[i];
        u16x4 o;
        o.x = f2b(v.x); o.y = f2b(v.y); o.z = f2b(v.z); o.w = f2b(v.w);
        *(u16x4*)&out[i] = o;
    }
}

// ---------------------------------------------------------------------------
// bf16 transpose: in [Bn][Sn][Dn] -> out [Bn][Dn][Sn]
// ---------------------------------------------------------------------------
__global__ __launch_bounds__(256) void k_transpose(const ushort_t* __restrict__ in,
                                                   ushort_t* __restrict__ out) {
    __shared__ ushort_t t[32][33];
    int z = blockIdx.z;
    int s0 = blockIdx.x * 32, d0 = blockIdx.y * 32;
    int tx = threadIdx.x & 31, ty = threadIdx.x >> 5;  // ty 0..7
    const ushort_t* ip = in + (size_t)z * Sn * Dn;
    ushort_t* op = out + (size_t)z * Sn * Dn;
#pragma unroll
    for (int i = 0; i < 4; ++i)
        t[ty + i * 8][tx] = ip[(size_t)(s0 + ty + i * 8) * Dn + d0 + tx];
    __syncthreads();
#pragma unroll
    for (int i = 0; i < 4; ++i)
        op[(size_t)(d0 + ty + i * 8) * Sn + s0 + tx] = t[tx][ty + i * 8];
}

// ---------------------------------------------------------------------------
// MFMA GEMM: C[M,N] = alpha * A[M,K] @ Bm[N,K]^T (+ R), bf16 in / f32 acc.
// 128x128 tile, BK=32, 256 threads (4 waves, each 64x64 = 4x4 MFMA frags).
// Optional outputs: f32 Cf and/or bf16 Cb. Batched via blockIdx.z strides.
// CAUSAL_SKIP: skip blocks entirely above the diagonal (M,N in same space).
// DIAG_KLIM:   clamp K loop at bm0+128 (PV with causal-zero probs beyond).
// ---------------------------------------------------------------------------
template <bool HAS_RES, bool OUT_F32, bool OUT_BF16, bool CAUSAL_SKIP, bool DIAG_KLIM>
__global__ __launch_bounds__(256)
void k_mfma_bt(const ushort_t* __restrict__ A, const ushort_t* __restrict__ Bm,
               const float* __restrict__ R, float* __restrict__ Cf,
               ushort_t* __restrict__ Cb, int M, int N, int K, float alpha,
               long long sA, long long sB, long long sC, long long sR) {
    int bm0 = blockIdx.y * 128;
    int bn0 = blockIdx.x * 128;
    if (CAUSAL_SKIP && bn0 > bm0 + 127) return;

    int zb = blockIdx.z;
    A += (long long)zb * sA;
    Bm += (long long)zb * sB;
    if (HAS_RES) R += (long long)zb * sR;
    if (OUT_F32) Cf += (long long)zb * sC;
    if (OUT_BF16) Cb += (long long)zb * sC;

    __shared__ alignas(16) ushort_t As[128 * 32];
    __shared__ alignas(16) ushort_t Bs[128 * 32];

    int tid = threadIdx.x;
    int lane = tid & 63;
    int wave = tid >> 6;
    int wr = wave >> 1, wc = wave & 1;  // 2x2 wave grid, 64x64 each

    int fr = lane & 15;        // frag row/col within 16
    int kq = lane >> 4;        // k-quad 0..3 -> k offset kq*8
    int rq = (lane >> 4) * 4;  // C row base

    f32x4 acc[4][4] = {};

    int kend = DIAG_KLIM ? (bm0 + 128 < K ? bm0 + 128 : K) : K;

    for (int k0 = 0; k0 < kend; k0 += 32) {
        // stage A,B tiles (128x32 bf16 each, linear [row][k])
#pragma unroll
        for (int c = 0; c < 2; ++c) {
            int idx = tid + c * 256;      // 0..511
            int r = idx >> 2;             // 0..127
            int co = (idx & 3) << 3;      // 0,8,16,24
            *(u16x8*)&As[r * 32 + co] =
                *(const u16x8*)&A[(size_t)(bm0 + r) * K + k0 + co];
            *(u16x8*)&Bs[r * 32 + co] =
                *(const u16x8*)&Bm[(size_t)(bn0 + r) * K + k0 + co];
        }
        __syncthreads();

        bf16x8 a[4], b[4];
#pragma unroll
        for (int m = 0; m < 4; ++m)
            a[m] = *(const bf16x8*)&As[(wr * 64 + m * 16 + fr) * 32 + kq * 8];
#pragma unroll
        for (int n = 0; n < 4; ++n)
            b[n] = *(const bf16x8*)&Bs[(wc * 64 + n * 16 + fr) * 32 + kq * 8];
#pragma unroll
        for (int m = 0; m < 4; ++m)
#pragma unroll
            for (int n = 0; n < 4; ++n)
                acc[m][n] = __builtin_amdgcn_mfma_f32_16x16x32_bf16(
                    a[m], b[n], acc[m][n], 0, 0, 0);
        __syncthreads();
    }

    // Epilogue: C/D layout col=lane&15, row=(lane>>4)*4+i (m89-verified)
#pragma unroll
    for (int m = 0; m < 4; ++m) {
#pragma unroll
        for (int n = 0; n < 4; ++n) {
            int gr = bm0 + wr * 64 + m * 16 + rq;
            int gc = bn0 + wc * 64 + n * 16 + fr;
#pragma unroll
            for (int i = 0; i < 4; ++i) {
                float v = acc[m][n][i] * alpha;
                size_t idx = (size_t)(gr + i) * N + gc;
                if (HAS_RES) v += R[idx];
                if (OUT_F32) Cf[idx] = v;
                if (OUT_BF16) Cb[idx] = f2b(v);
            }
        }
    }
}

// ---------------------------------------------------------------------------
// Causal softmax: read f32 scores row, write bf16 probs (0 beyond diagonal)
// ---------------------------------------------------------------------------
__global__ __launch_bounds__(256) void k_softmax(const float* __restrict__ Sc,
                                                 ushort_t* __restrict__ Pb) {
    int bs = blockIdx.x;
    int b = bs / Sn, s = bs % Sn;
    const float* row = Sc + (size_t)b * Sn * Sn + (size_t)s * Sn;
    ushort_t* prow = Pb + (size_t)b * Sn * Sn + (size_t)s * Sn;
    int tid = threadIdx.x;
    int n = s + 1;

    __shared__ float red[256];

    float m = -INFINITY;
    for (int t = tid; t < n; t += 256) m = fmaxf(m, row[t]);
    red[tid] = m;
    __syncthreads();
    for (int off = 128; off > 0; off >>= 1) {
        if (tid < off) red[tid] = fmaxf(red[tid], red[tid + off]);
        __syncthreads();
    }
    m = red[0];
    __syncthreads();

    float sum = 0.0f;
    for (int t = tid; t < n; t += 256) sum += expf(row[t] - m);
    red[tid] = sum;
    __syncthreads();
    for (int off = 128; off > 0; off >>= 1) {
        if (tid < off) red[tid] += red[tid + off];
        __syncthreads();
    }
    float inv = 1.0f / red[0];

    for (int t = tid; t < Sn; t += 256)
        prow[t] = (t < n) ? f2b(expf(row[t] - m) * inv) : (ushort_t)0;
}

// ---------------------------------------------------------------------------
static void launch_layer(const float* XfIn, float* XfOut, ushort_t* Xb,
                         const ushort_t* Wqk, const ushort_t* Wov, ushort_t* Qb,
                         ushort_t* Vb, ushort_t* Vt, float* Sc, ushort_t* Pb,
                         hipStream_t stream) {
    // Q = Xb @ Wqk^T -> bf16 ; V = Xb @ Wov^T -> bf16
    k_mfma_bt<false, false, true, false, false><<<dim3(2, 32, 1), 256, 0, stream>>>(
        Xb, Wqk, nullptr, nullptr, Qb, BSn, Dn, Dn, 1.0f, 0, 0, 0, 0);
    k_mfma_bt<false, false, true, false, false><<<dim3(2, 32, 1), 256, 0, stream>>>(
        Xb, Wov, nullptr, nullptr, Vb, BSn, Dn, Dn, 1.0f, 0, 0, 0, 0);
    // Vt[b][d][s] = V[b][s][d]
    k_transpose<<<dim3(Sn / 32, Dn / 32, Bn), 256, 0, stream>>>(Vb, Vt);
    // scores = 16 * Q @ Xb^T (batched, causal blocks skipped)
    k_mfma_bt<false, true, false, true, false><<<dim3(Sn / 128, Sn / 128, Bn), 256, 0, stream>>>(
        Qb, Xb, nullptr, Sc, nullptr, Sn, Sn, Dn, 16.0f,
        (long long)Sn * Dn, (long long)Sn * Dn, (long long)Sn * Sn, 0);
    // softmax -> bf16 probs (zeros in masked region)
    k_softmax<<<Bn * Sn, 256, 0, stream>>>(Sc, Pb);
    // Xout = Pb @ Vt^T + XfIn ; also Xb = bf16(Xout), K clamped at diagonal
    k_mfma_bt<true, true, true, false, true><<<dim3(Dn / 128, Sn / 128, Bn), 256, 0, stream>>>(
        Pb, Vt, XfIn, XfOut, Xb, Sn, Dn, Sn, 1.0f,
        (long long)Sn * Sn, (long long)Dn * Sn, (long long)Sn * Dn,
        (long long)Sn * Dn);
}

extern "C" void kernel_launch(void* const* d_in, const int* in_sizes, int n_in,
                              void* d_out, int out_size, void* d_ws,
                              size_t ws_size, hipStream_t stream) {
    const int* inp = (const int*)d_in[0];
    // d_in[1] = mask — causal by construction, not read
    const float* E = (const float*)d_in[2];
    const float* P = (const float*)d_in[3];
    const float* WQK1 = (const float*)d_in[4];
    const float* WOV1 = (const float*)d_in[5];
    const float* WQK2 = (const float*)d_in[6];
    const float* WOV2 = (const float*)d_in[7];
    const float* WF = (const float*)d_in[8];
    const float* U = (const float*)d_in[9];
    float* out = (float*)d_out;

    char* p = (char*)d_ws;
    auto alloc = [&](size_t bytes) {
        void* r = (void*)p;
        p += (bytes + 255) & ~(size_t)255;
        return r;
    };

    float* XfA = (float*)alloc((size_t)BSn * Dn * 4);
    float* XfB = (float*)alloc((size_t)BSn * Dn * 4);
    float* Sc = (float*)alloc((size_t)Bn * Sn * Sn * 4);
    ushort_t* Xb = (ushort_t*)alloc((size_t)BSn * Dn * 2);
    ushort_t* Qb = (ushort_t*)alloc((size_t)BSn * Dn * 2);
    ushort_t* Vb = (ushort_t*)alloc((size_t)BSn * Dn * 2);
    ushort_t* Vt = (ushort_t*)alloc((size_t)BSn * Dn * 2);
    ushort_t* Fb = (ushort_t*)alloc((size_t)BSn * Dn * 2);
    ushort_t* Pb = (ushort_t*)alloc((size_t)Bn * Sn * Sn * 2);
    ushort_t* Wq1 = (ushort_t*)alloc((size_t)Dn * Dn * 2);
    ushort_t* Wo1 = (ushort_t*)alloc((size_t)Dn * Dn * 2);
    ushort_t* Wq2 = (ushort_t*)alloc((size_t)Dn * Dn * 2);
    ushort_t* Wo2 = (ushort_t*)alloc((size_t)Dn * Dn * 2);
    ushort_t* Wfb = (ushort_t*)alloc((size_t)Dn * Dn * 2);
    ushort_t* Ub = (ushort_t*)alloc((size_t)Vn * Dn * 2);

    // weight conversions
    int wn = Dn * Dn;
    int wg = (wn / 4 + 255) / 256;
    k_convert<<<wg, 256, 0, stream>>>(WQK1, Wq1, wn);
    k_convert<<<wg, 256, 0, stream>>>(WOV1, Wo1, wn);
    k_convert<<<wg, 256, 0, stream>>>(WQK2, Wq2, wn);
    k_convert<<<wg, 256, 0, stream>>>(WOV2, Wo2, wn);
    k_convert<<<wg, 256, 0, stream>>>(WF, Wfb, wn);
    int un = Vn * Dn;
    k_convert<<<(un / 4 + 255) / 256, 256, 0, stream>>>(U, Ub, un);

    // X = E[input] + P (f32 + bf16)
    k_embed<<<BSn, 256, 0, stream>>>(inp, E, P, XfA, Xb);

    // two attention blocks (ping-pong XfA <-> XfB; Xb tracks current X)
    launch_layer(XfA, XfB, Xb, Wq1, Wo1, Qb, Vb, Vt, Sc, Pb, stream);
    launch_layer(XfB, XfA, Xb, Wq2, Wo2, Qb, Vb, Vt, Sc, Pb, stream);

    // FFN residual: Fb = bf16(XfA + Xb @ Wf^T)
    k_mfma_bt<true, false, true, false, false><<<dim3(2, 32, 1), 256, 0, stream>>>(
        Xb, Wfb, XfA, nullptr, Fb, BSn, Dn, Dn, 1.0f, 0, 0, 0, 0);

    // logits = Fb @ Ub^T -> d_out (f32)
    k_mfma_bt<false, true, false, false, false><<<dim3(Vn / 128, BSn / 128, 1), 256, 0, stream>>>(
        Fb, Ub, nullptr, out, nullptr, BSn, Vn, Dn, 1.0f, 0, 0, 0, 0);
}

// Round 3
// 407.810 us; speedup vs baseline: 3.6025x; 1.0232x over previous
//
#include <hip/hip_runtime.h>
#include <math.h>

#define Bn 2
#define Sn 2048
#define Vn 32000
#define Dn 256
#define BSn (Bn * Sn)

typedef unsigned short u16;
typedef __attribute__((ext_vector_type(8))) __bf16 bf16x8;
typedef __attribute__((ext_vector_type(4))) float f32x4;
typedef __attribute__((ext_vector_type(8))) unsigned short u16x8;
typedef __attribute__((ext_vector_type(4))) unsigned short u16x4;

__device__ __forceinline__ u16 f2b(float v) {
    union { __bf16 b; u16 u; } c;
    c.b = (__bf16)v;
    return c.u;
}

// async global->LDS, 16B per lane; LDS dest must be linear in lane order
#define GLOAD16(gp, lp)                                          \
    __builtin_amdgcn_global_load_lds(                            \
        (const __attribute__((address_space(1))) void*)(gp),     \
        (__attribute__((address_space(3))) void*)(lp), 16, 0, 0)

// ---------------------------------------------------------------------------
// Embed: Xf = E[tok] + P (f32), Xb = bf16(Xf)
// ---------------------------------------------------------------------------
__global__ __launch_bounds__(256) void k_embed(const int* __restrict__ inp,
                                               const float* __restrict__ E,
                                               const float* __restrict__ P,
                                               float* __restrict__ Xf,
                                               u16* __restrict__ Xb) {
    int bs = blockIdx.x;
    int d = threadIdx.x;
    int tok = inp[bs];
    int s = bs % Sn;
    float v = E[(size_t)tok * Dn + d] + P[(size_t)s * Dn + d];
    Xf[(size_t)bs * Dn + d] = v;
    Xb[(size_t)bs * Dn + d] = f2b(v);
}

// ---------------------------------------------------------------------------
// Batched weight convert: 5 D*D matrices f32 -> bf16 (dst may interleave QV)
// ---------------------------------------------------------------------------
__global__ __launch_bounds__(256) void k_convert_w(
    const float* s0, u16* d0, const float* s1, u16* d1, const float* s2,
    u16* d2, const float* s3, u16* d3, const float* s4, u16* d4) {
    const float* src;
    u16* dst;
    switch (blockIdx.y) {
        case 0: src = s0; dst = d0; break;
        case 1: src = s1; dst = d1; break;
        case 2: src = s2; dst = d2; break;
        case 3: src = s3; dst = d3; break;
        default: src = s4; dst = d4; break;
    }
    int i = (blockIdx.x * 256 + threadIdx.x) * 4;  // Dn*Dn = 65536 = 64 blocks
    float4 v = *(const float4*)&src[i];
    u16x4 o;
    o.x = f2b(v.x); o.y = f2b(v.y); o.z = f2b(v.z); o.w = f2b(v.w);
    *(u16x4*)&dst[i] = o;
}

// ---------------------------------------------------------------------------
// bf16 transpose: in [Bn][Sn][ldin] (+col offset pre-added) -> out [Bn][Dn][Sn]
// ---------------------------------------------------------------------------
__global__ __launch_bounds__(256) void k_transpose(const u16* __restrict__ in,
                                                   u16* __restrict__ out,
                                                   int ldin) {
    __shared__ u16 t[32][33];
    int z = blockIdx.z;
    int s0 = blockIdx.x * 32, d0 = blockIdx.y * 32;
    int tx = threadIdx.x & 31, ty = threadIdx.x >> 5;
    const u16* ip = in + (size_t)z * Sn * ldin;
    u16* op = out + (size_t)z * Dn * Sn;
#pragma unroll
    for (int i = 0; i < 4; ++i)
        t[ty + i * 8][tx] = ip[(size_t)(s0 + ty + i * 8) * ldin + d0 + tx];
    __syncthreads();
#pragma unroll
    for (int i = 0; i < 4; ++i)
        op[(size_t)(d0 + ty + i * 8) * Sn + s0 + tx] = t[tx][ty + i * 8];
}

// ---------------------------------------------------------------------------
// MFMA GEMM: C[M,N] = alpha * A[M,K] @ B[N,K]^T (+R). bf16 A; B bf16 or f32
// (B_F32: convert during staging). 128x128 tile, BK=32, 256 thr, 2x2 waves.
// A staged via global_load_lds (LDS linear in lane order). Optional chunked
// block remap (CHUNK x-tiles per chunk) for L2 locality on wide-N GEMMs.
// ---------------------------------------------------------------------------
template <bool HAS_RES, bool OUT_F32, bool OUT_BF16, bool CAUSAL_SKIP,
          bool DIAG_KLIM, bool B_F32, int CHUNK>
__global__ __launch_bounds__(256)
void k_mfma(const u16* __restrict__ A, const void* __restrict__ Bv,
            const float* __restrict__ R, float* __restrict__ Cf,
            u16* __restrict__ Cb, int M, int N, int K, int lda, int ldb,
            int ldc, float alpha, long long sA, long long sB, long long sC,
            long long sR, int ytiles) {
    int bx, by;
    if (CHUNK > 0) {
        int per = CHUNK * ytiles;
        int bid = blockIdx.x;
        int ch = bid / per, rr = bid % per;
        bx = ch * CHUNK + rr % CHUNK;
        by = rr / CHUNK;
    } else {
        bx = blockIdx.x;
        by = blockIdx.y;
    }
    int bm0 = by * 128;
    int bn0 = bx * 128;
    if (CAUSAL_SKIP && bn0 > bm0 + 127) return;

    int zb = blockIdx.z;
    A += (long long)zb * sA;
    if (HAS_RES) R += (long long)zb * sR;
    if (OUT_F32) Cf += (long long)zb * sC;
    if (OUT_BF16) Cb += (long long)zb * sC;

    __shared__ alignas(16) u16 As[128 * 32];
    __shared__ alignas(16) u16 Bs[128 * 32];

    int tid = threadIdx.x;
    int lane = tid & 63;
    int wave = tid >> 6;
    int wr = wave >> 1, wc = wave & 1;

    int fr = lane & 15;
    int kq = lane >> 4;
    int rq = (lane >> 4) * 4;

    f32x4 acc[4][4] = {};

    int kend = DIAG_KLIM ? (bm0 + 128 < K ? bm0 + 128 : K) : K;

    for (int k0 = 0; k0 < kend; k0 += 32) {
#pragma unroll
        for (int c = 0; c < 2; ++c) {
            int idx = tid + c * 256;
            int r = idx >> 2, co = (idx & 3) << 3;
            GLOAD16(&A[(size_t)(bm0 + r) * lda + k0 + co], &As[idx * 8]);
        }
        if (B_F32) {
            const float* Bf = (const float*)Bv + (long long)zb * sB;
#pragma unroll
            for (int c = 0; c < 2; ++c) {
                int idx = tid + c * 256;
                int r = idx >> 2, co = (idx & 3) << 3;
                const float* src = &Bf[(size_t)(bn0 + r) * ldb + k0 + co];
                float4 v0 = *(const float4*)src;
                float4 v1 = *(const float4*)(src + 4);
                u16x8 o;
                o[0] = f2b(v0.x); o[1] = f2b(v0.y);
                o[2] = f2b(v0.z); o[3] = f2b(v0.w);
                o[4] = f2b(v1.x); o[5] = f2b(v1.y);
                o[6] = f2b(v1.z); o[7] = f2b(v1.w);
                *(u16x8*)&Bs[idx * 8] = o;
            }
        } else {
            const u16* Bb = (const u16*)Bv + (long long)zb * sB;
#pragma unroll
            for (int c = 0; c < 2; ++c) {
                int idx = tid + c * 256;
                int r = idx >> 2, co = (idx & 3) << 3;
                GLOAD16(&Bb[(size_t)(bn0 + r) * ldb + k0 + co], &Bs[idx * 8]);
            }
        }
        __syncthreads();

        bf16x8 a[4], b[4];
#pragma unroll
        for (int m = 0; m < 4; ++m)
            a[m] = *(const bf16x8*)&As[(wr * 64 + m * 16 + fr) * 32 + kq * 8];
#pragma unroll
        for (int n = 0; n < 4; ++n)
            b[n] = *(const bf16x8*)&Bs[(wc * 64 + n * 16 + fr) * 32 + kq * 8];
#pragma unroll
        for (int m = 0; m < 4; ++m)
#pragma unroll
            for (int n = 0; n < 4; ++n)
                acc[m][n] = __builtin_amdgcn_mfma_f32_16x16x32_bf16(
                    a[m], b[n], acc[m][n], 0, 0, 0);
        __syncthreads();
    }

    // C/D layout: col = lane&15, row = (lane>>4)*4 + i
#pragma unroll
    for (int m = 0; m < 4; ++m) {
#pragma unroll
        for (int n = 0; n < 4; ++n) {
            int gr = bm0 + wr * 64 + m * 16 + rq;
            int gc = bn0 + wc * 64 + n * 16 + fr;
#pragma unroll
            for (int i = 0; i < 4; ++i) {
                float v = acc[m][n][i] * alpha;
                size_t idx = (size_t)(gr + i) * ldc + gc;
                if (HAS_RES) v += R[idx];
                if (OUT_F32) Cf[idx] = v;
                if (OUT_BF16) Cb[idx] = f2b(v);
            }
        }
    }
}

// ---------------------------------------------------------------------------
// Causal softmax: f32 scores row -> bf16 probs; writes cols [0, ceil128(n))
// (PV clamps K at the diagonal block edge, so nothing beyond is read)
// ---------------------------------------------------------------------------
__global__ __launch_bounds__(256) void k_softmax(const float* __restrict__ Sc,
                                                 u16* __restrict__ Pb) {
    int bs = blockIdx.x;
    int b = bs / Sn, s = bs % Sn;
    const float* row = Sc + (size_t)b * Sn * Sn + (size_t)s * Sn;
    u16* prow = Pb + (size_t)b * Sn * Sn + (size_t)s * Sn;
    int tid = threadIdx.x;
    int n = s + 1;
    int nc = (n + 127) & ~127;

    __shared__ float red[256];

    float m = -INFINITY;
    for (int t = tid; t < n; t += 256) m = fmaxf(m, row[t]);
    red[tid] = m;
    __syncthreads();
    for (int off = 128; off > 0; off >>= 1) {
        if (tid < off) red[tid] = fmaxf(red[tid], red[tid + off]);
        __syncthreads();
    }
    m = red[0];
    __syncthreads();

    float sum = 0.0f;
    for (int t = tid; t < n; t += 256) sum += expf(row[t] - m);
    red[tid] = sum;
    __syncthreads();
    for (int off = 128; off > 0; off >>= 1) {
        if (tid < off) red[tid] += red[tid + off];
        __syncthreads();
    }
    float inv = 1.0f / red[0];

    for (int t = tid; t < nc; t += 256)
        prow[t] = (t < n) ? f2b(expf(row[t] - m) * inv) : (u16)0;
}

// ---------------------------------------------------------------------------
static void launch_layer(const float* XfIn, float* XfOut, u16* Xb,
                         const u16* Wqv, u16* QVb, u16* Vt, float* Sc, u16* Pb,
                         hipStream_t stream) {
    // QV = Xb @ Wqv^T  (Q = cols 0..255, V = cols 256..511)
    k_mfma<false, false, true, false, false, false, 0>
        <<<dim3(4, 32, 1), 256, 0, stream>>>(
            Xb, Wqv, nullptr, nullptr, QVb, BSn, 512, Dn, Dn, Dn, 512, 1.0f,
            0, 0, 0, 0, 0);
    // Vt[b][d][s] = V[b][s][d]
    k_transpose<<<dim3(Sn / 32, Dn / 32, Bn), 256, 0, stream>>>(QVb + Dn, Vt,
                                                                512);
    // scores = 16 * Q @ Xb^T (batched, causal blocks skipped)
    k_mfma<false, true, false, true, false, false, 0>
        <<<dim3(Sn / 128, Sn / 128, Bn), 256, 0, stream>>>(
            QVb, Xb, nullptr, Sc, nullptr, Sn, Sn, Dn, 512, Dn, Sn, 16.0f,
            (long long)Sn * 512, (long long)Sn * Dn, (long long)Sn * Sn, 0, 0);
    // softmax -> bf16 probs
    k_softmax<<<Bn * Sn, 256, 0, stream>>>(Sc, Pb);
    // Xout = Pb @ Vt^T + XfIn ; Xb = bf16(Xout); K clamped at diagonal
    k_mfma<true, true, true, false, true, false, 0>
        <<<dim3(Dn / 128, Sn / 128, Bn), 256, 0, stream>>>(
            Pb, Vt, XfIn, XfOut, Xb, Sn, Dn, Sn, Sn, Sn, Dn, 1.0f,
            (long long)Sn * Sn, (long long)Dn * Sn, (long long)Sn * Dn,
            (long long)Sn * Dn, 0);
}

extern "C" void kernel_launch(void* const* d_in, const int* in_sizes, int n_in,
                              void* d_out, int out_size, void* d_ws,
                              size_t ws_size, hipStream_t stream) {
    const int* inp = (const int*)d_in[0];
    // d_in[1] = mask — causal by construction, not read
    const float* E = (const float*)d_in[2];
    const float* P = (const float*)d_in[3];
    const float* WQK1 = (const float*)d_in[4];
    const float* WOV1 = (const float*)d_in[5];
    const float* WQK2 = (const float*)d_in[6];
    const float* WOV2 = (const float*)d_in[7];
    const float* WF = (const float*)d_in[8];
    const float* U = (const float*)d_in[9];
    float* out = (float*)d_out;

    char* p = (char*)d_ws;
    auto alloc = [&](size_t bytes) {
        void* r = (void*)p;
        p += (bytes + 255) & ~(size_t)255;
        return r;
    };

    float* XfA = (float*)alloc((size_t)BSn * Dn * 4);
    float* XfB = (float*)alloc((size_t)BSn * Dn * 4);
    float* Sc = (float*)alloc((size_t)Bn * Sn * Sn * 4);
    u16* Xb = (u16*)alloc((size_t)BSn * Dn * 2);
    u16* QVb = (u16*)alloc((size_t)BSn * 512 * 2);
    u16* Vt = (u16*)alloc((size_t)Bn * Dn * Sn * 2);
    u16* Fb = (u16*)alloc((size_t)BSn * Dn * 2);
    u16* Pb = (u16*)alloc((size_t)Bn * Sn * Sn * 2);
    u16* Wqv1 = (u16*)alloc((size_t)512 * Dn * 2);
    u16* Wqv2 = (u16*)alloc((size_t)512 * Dn * 2);
    u16* Wfb = (u16*)alloc((size_t)Dn * Dn * 2);

    // weight converts: WQK1/WOV1 -> Wqv1 halves, WQK2/WOV2 -> Wqv2, WF -> Wfb
    k_convert_w<<<dim3(64, 5), 256, 0, stream>>>(
        WQK1, Wqv1, WOV1, Wqv1 + (size_t)Dn * Dn, WQK2, Wqv2, WOV2,
        Wqv2 + (size_t)Dn * Dn, WF, Wfb);

    // X = E[input] + P
    k_embed<<<BSn, 256, 0, stream>>>(inp, E, P, XfA, Xb);

    // two attention blocks
    launch_layer(XfA, XfB, Xb, Wqv1, QVb, Vt, Sc, Pb, stream);
    launch_layer(XfB, XfA, Xb, Wqv2, QVb, Vt, Sc, Pb, stream);

    // FFN residual: Fb = bf16(XfA + Xb @ Wf^T)
    k_mfma<true, false, true, false, false, false, 0>
        <<<dim3(2, 32, 1), 256, 0, stream>>>(
            Xb, Wfb, XfA, nullptr, Fb, BSn, Dn, Dn, Dn, Dn, Dn, 1.0f, 0, 0, 0,
            0, 0);

    // logits = Fb @ U^T (U read as f32, converted in staging), chunked remap
    k_mfma<false, true, false, false, false, true, 25>
        <<<dim3((Vn / 128) * (BSn / 128), 1, 1), 256, 0, stream>>>(
            Fb, U, nullptr, out, nullptr, BSn, Vn, Dn, Dn, Dn, Vn, 1.0f, 0, 0,
            0, 0, BSn / 128);
}

// Round 4
// 328.587 us; speedup vs baseline: 4.4711x; 1.2411x over previous
//
#include <hip/hip_runtime.h>
#include <math.h>

#define Bn 2
#define Sn 2048
#define Vn 32000
#define Dn 256
#define BSn (Bn * Sn)

typedef unsigned short u16;
typedef __attribute__((ext_vector_type(8))) __bf16 bf16x8;
typedef __attribute__((ext_vector_type(4))) float f32x4;
typedef __attribute__((ext_vector_type(8))) unsigned short u16x8;
typedef __attribute__((ext_vector_type(4))) unsigned short u16x4;

__device__ __forceinline__ u16 f2b(float v) {
    union { __bf16 b; u16 u; } c;
    c.b = (__bf16)v;
    return c.u;
}

// async global->LDS, 16B per lane; LDS dest must be linear in lane order
#define GLOAD16(gp, lp)                                          \
    __builtin_amdgcn_global_load_lds(                            \
        (const __attribute__((address_space(1))) void*)(gp),     \
        (__attribute__((address_space(3))) void*)(lp), 16, 0, 0)

__device__ __forceinline__ float wred_max(float v) {
#pragma unroll
    for (int o = 32; o; o >>= 1) v = fmaxf(v, __shfl_xor(v, o, 64));
    return v;
}
__device__ __forceinline__ float wred_sum(float v) {
#pragma unroll
    for (int o = 32; o; o >>= 1) v += __shfl_xor(v, o, 64);
    return v;
}

// ---------------------------------------------------------------------------
// Embed: Xf = E[tok] + P (f32), Xb = bf16(Xf)
// ---------------------------------------------------------------------------
__global__ __launch_bounds__(256) void k_embed(const int* __restrict__ inp,
                                               const float* __restrict__ E,
                                               const float* __restrict__ P,
                                               float* __restrict__ Xf,
                                               u16* __restrict__ Xb) {
    int bs = blockIdx.x;
    int d = threadIdx.x;
    int tok = inp[bs];
    int s = bs % Sn;
    float v = E[(size_t)tok * Dn + d] + P[(size_t)s * Dn + d];
    Xf[(size_t)bs * Dn + d] = v;
    Xb[(size_t)bs * Dn + d] = f2b(v);
}

// ---------------------------------------------------------------------------
// Generic f32 -> bf16 convert (n multiple of 1024)
// ---------------------------------------------------------------------------
__global__ __launch_bounds__(256) void k_convert(const float* __restrict__ in,
                                                 u16* __restrict__ out) {
    int i = (blockIdx.x * 256 + threadIdx.x) * 4;
    float4 v = *(const float4*)&in[i];
    u16x4 o;
    o.x = f2b(v.x); o.y = f2b(v.y); o.z = f2b(v.z); o.w = f2b(v.w);
    *(u16x4*)&out[i] = o;
}

// ---------------------------------------------------------------------------
// Batched weight convert: 5 D*D matrices f32 -> bf16
// ---------------------------------------------------------------------------
__global__ __launch_bounds__(256) void k_convert_w(
    const float* s0, u16* d0, const float* s1, u16* d1, const float* s2,
    u16* d2, const float* s3, u16* d3, const float* s4, u16* d4) {
    const float* src;
    u16* dst;
    switch (blockIdx.y) {
        case 0: src = s0; dst = d0; break;
        case 1: src = s1; dst = d1; break;
        case 2: src = s2; dst = d2; break;
        case 3: src = s3; dst = d3; break;
        default: src = s4; dst = d4; break;
    }
    int i = (blockIdx.x * 256 + threadIdx.x) * 4;
    float4 v = *(const float4*)&src[i];
    u16x4 o;
    o.x = f2b(v.x); o.y = f2b(v.y); o.z = f2b(v.z); o.w = f2b(v.w);
    *(u16x4*)&dst[i] = o;
}

// ---------------------------------------------------------------------------
// MFMA GEMM: C[M,N] = alpha * A[M,K] @ B[N,K]^T (+R). bf16 in, f32 acc.
// 128x128 tile, BK=32, 256 thr (2x2 waves, 64x64 each), dual-buffer LDS
// 2-phase pipeline (stage next k-tile before compute of current; one barrier
// per k-step whose implicit vmcnt(0) drain covers the async stage).
// QV_SPLIT: x-tiles with bn0>=256 scatter-write transposed bf16 to Ct[b][d][s].
// CHUNK>0: 1-D launch, chunked x-remap for L2 locality on wide-N GEMMs.
// ---------------------------------------------------------------------------
template <bool HAS_RES, bool OUT_F32, bool OUT_BF16, bool CAUSAL_SKIP,
          bool DIAG_KLIM, bool QV_SPLIT, int CHUNK>
__global__ __launch_bounds__(256)
void k_mfma(const u16* __restrict__ A, const u16* __restrict__ Bb,
            const float* __restrict__ R, float* __restrict__ Cf,
            u16* __restrict__ Cb, u16* __restrict__ Ct, int M, int N, int K,
            int lda, int ldb, int ldc, float alpha, long long sA, long long sB,
            long long sC, long long sR, int ytiles) {
    int bx, by;
    if (CHUNK > 0) {
        int per = CHUNK * ytiles;
        int bid = blockIdx.x;
        int ch = bid / per, rr = bid % per;
        bx = ch * CHUNK + rr % CHUNK;
        by = rr / CHUNK;
    } else {
        bx = blockIdx.x;
        by = blockIdx.y;
    }
    int bm0 = by * 128;
    int bn0 = bx * 128;
    if (CAUSAL_SKIP && bn0 > bm0 + 127) return;

    int zb = blockIdx.z;
    A += (long long)zb * sA;
    Bb += (long long)zb * sB;
    if (HAS_RES) R += (long long)zb * sR;
    if (OUT_F32) Cf += (long long)zb * sC;
    if (OUT_BF16) Cb += (long long)zb * sC;

    __shared__ alignas(16) u16 As[2][128 * 32];
    __shared__ alignas(16) u16 Bs[2][128 * 32];

    int tid = threadIdx.x;
    int lane = tid & 63;
    int wave = tid >> 6;
    int wr = wave >> 1, wc = wave & 1;

    int fr = lane & 15;
    int kq = lane >> 4;
    int rq = kq * 4;

    f32x4 acc[4][4] = {};

    int kend = DIAG_KLIM ? (bm0 + 128 < K ? bm0 + 128 : K) : K;
    int nt = kend >> 5;

    // stage k-tile (A 128x32 + B 128x32 bf16) into buffer `buf`
    auto STAGE = [&](int buf, int k0) {
#pragma unroll
        for (int c = 0; c < 2; ++c) {
            int idx = tid + c * 256;
            int r = idx >> 2, co = (idx & 3) << 3;
            GLOAD16(&A[(size_t)(bm0 + r) * lda + k0 + co], &As[buf][idx * 8]);
            GLOAD16(&Bb[(size_t)(bn0 + r) * ldb + k0 + co], &Bs[buf][idx * 8]);
        }
    };

    STAGE(0, 0);
    __syncthreads();  // implicit vmcnt(0) drain + barrier

    for (int t = 0; t < nt; ++t) {
        int cur = t & 1;
        if (t + 1 < nt) STAGE(cur ^ 1, (t + 1) << 5);

        bf16x8 a[4], b[4];
#pragma unroll
        for (int m = 0; m < 4; ++m)
            a[m] = *(const bf16x8*)&As[cur][(wr * 64 + m * 16 + fr) * 32 + kq * 8];
#pragma unroll
        for (int n = 0; n < 4; ++n)
            b[n] = *(const bf16x8*)&Bs[cur][(wc * 64 + n * 16 + fr) * 32 + kq * 8];
#pragma unroll
        for (int m = 0; m < 4; ++m)
#pragma unroll
            for (int n = 0; n < 4; ++n)
                acc[m][n] = __builtin_amdgcn_mfma_f32_16x16x32_bf16(
                    a[m], b[n], acc[m][n], 0, 0, 0);
        __syncthreads();
    }

    // ---- epilogue; C/D layout: col = lane&15, row = (lane>>4)*4 + i ----
    if (QV_SPLIT && bn0 >= 256) {
        // transposed V write: Ct[b][d][s] = acc(s-row, d-col)
#pragma unroll
        for (int m = 0; m < 4; ++m) {
#pragma unroll
            for (int n = 0; n < 4; ++n) {
                int gr = bm0 + wr * 64 + m * 16 + rq;        // s-global
                int gc = bn0 + wc * 64 + n * 16 + fr - 256;  // d
                int bb = gr / Sn;
                int ss = gr % Sn;
                u16x4 o;
#pragma unroll
                for (int i = 0; i < 4; ++i) o[i] = f2b(acc[m][n][i]);
                *(u16x4*)&Ct[((size_t)bb * Dn + gc) * Sn + ss] = o;
            }
        }
        return;
    }

#pragma unroll
    for (int m = 0; m < 4; ++m) {
#pragma unroll
        for (int n = 0; n < 4; ++n) {
            int gr = bm0 + wr * 64 + m * 16 + rq;
            int gc = bn0 + wc * 64 + n * 16 + fr;
#pragma unroll
            for (int i = 0; i < 4; ++i) {
                float v = acc[m][n][i] * alpha;
                size_t idx = (size_t)(gr + i) * ldc + gc;
                if (HAS_RES) v += R[idx];
                if (OUT_F32) Cf[idx] = v;
                if (OUT_BF16) Cb[idx] = f2b(v);
            }
        }
    }
}

// ---------------------------------------------------------------------------
// Single-pass causal softmax: row (2048 f32) in 8 regs; one read, one expf
// pass; writes bf16 probs in cols [0, ceil128(n)) (zeros beyond diagonal).
// ---------------------------------------------------------------------------
__global__ __launch_bounds__(256) void k_softmax(const float* __restrict__ Sc,
                                                 u16* __restrict__ Pb) {
    int bs = blockIdx.x;
    int b = bs >> 11, s = bs & 2047;
    const float* row = Sc + ((size_t)b << 22) + ((size_t)s << 11);
    u16* prow = Pb + ((size_t)b << 22) + ((size_t)s << 11);
    int tid = threadIdx.x;
    int n = s + 1;
    int nc = (n + 127) & ~127;

    float v[8];
#pragma unroll
    for (int j = 0; j < 8; ++j) {
        int t = tid + j * 256;
        v[j] = (t < n) ? row[t] : -INFINITY;
    }

    float m = v[0];
#pragma unroll
    for (int j = 1; j < 8; ++j) m = fmaxf(m, v[j]);
    m = wred_max(m);

    __shared__ float red[8];
    int lane = tid & 63, w = tid >> 6;
    if (lane == 0) red[w] = m;
    __syncthreads();
    m = fmaxf(fmaxf(red[0], red[1]), fmaxf(red[2], red[3]));

    float sum = 0.0f;
#pragma unroll
    for (int j = 0; j < 8; ++j) {
        v[j] = __expf(v[j] - m);  // exp(-inf)=0 handles the mask
        sum += v[j];
    }
    sum = wred_sum(sum);
    if (lane == 0) red[4 + w] = sum;
    __syncthreads();
    float inv = 1.0f / (red[4] + red[5] + red[6] + red[7]);

#pragma unroll
    for (int j = 0; j < 8; ++j) {
        int t = tid + j * 256;
        if (t < nc) prow[t] = f2b(v[j] * inv);
    }
}

// ---------------------------------------------------------------------------
static void launch_layer(const float* XfIn, float* XfOut, u16* Xb,
                         const u16* Wqv, u16* Qb, u16* Vt, float* Sc, u16* Pb,
                         hipStream_t stream) {
    // QV = Xb @ Wqv^T ; bx<2 -> Qb (normal), bx>=2 -> Vt (transposed)
    k_mfma<false, false, true, false, false, true, 0>
        <<<dim3(4, 32, 1), 256, 0, stream>>>(
            Xb, Wqv, nullptr, nullptr, Qb, Vt, BSn, 512, Dn, Dn, Dn, Dn, 1.0f,
            0, 0, 0, 0, 0);
    // scores = 16 * Qb @ Xb^T (batched, causal blocks skipped)
    k_mfma<false, true, false, true, false, false, 0>
        <<<dim3(Sn / 128, Sn / 128, Bn), 256, 0, stream>>>(
            Qb, Xb, nullptr, Sc, nullptr, nullptr, Sn, Sn, Dn, Dn, Dn, Sn,
            16.0f, (long long)Sn * Dn, (long long)Sn * Dn, (long long)Sn * Sn,
            0, 0);
    // softmax -> bf16 probs
    k_softmax<<<Bn * Sn, 256, 0, stream>>>(Sc, Pb);
    // Xout = Pb @ Vt^T + XfIn ; Xb = bf16(Xout); K clamped at diagonal
    k_mfma<true, true, true, false, true, false, 0>
        <<<dim3(Dn / 128, Sn / 128, Bn), 256, 0, stream>>>(
            Pb, Vt, XfIn, XfOut, Xb, nullptr, Sn, Dn, Sn, Sn, Sn, Dn, 1.0f,
            (long long)Sn * Sn, (long long)Dn * Sn, (long long)Sn * Dn,
            (long long)Sn * Dn, 0);
}

extern "C" void kernel_launch(void* const* d_in, const int* in_sizes, int n_in,
                              void* d_out, int out_size, void* d_ws,
                              size_t ws_size, hipStream_t stream) {
    const int* inp = (const int*)d_in[0];
    // d_in[1] = mask — causal by construction, not read
    const float* E = (const float*)d_in[2];
    const float* P = (const float*)d_in[3];
    const float* WQK1 = (const float*)d_in[4];
    const float* WOV1 = (const float*)d_in[5];
    const float* WQK2 = (const float*)d_in[6];
    const float* WOV2 = (const float*)d_in[7];
    const float* WF = (const float*)d_in[8];
    const float* U = (const float*)d_in[9];
    float* out = (float*)d_out;

    char* p = (char*)d_ws;
    auto alloc = [&](size_t bytes) {
        void* r = (void*)p;
        p += (bytes + 255) & ~(size_t)255;
        return r;
    };

    float* XfA = (float*)alloc((size_t)BSn * Dn * 4);
    float* XfB = (float*)alloc((size_t)BSn * Dn * 4);
    float* Sc = (float*)alloc((size_t)Bn * Sn * Sn * 4);
    u16* Xb = (u16*)alloc((size_t)BSn * Dn * 2);
    u16* Qb = (u16*)alloc((size_t)BSn * Dn * 2);
    u16* Vt = (u16*)alloc((size_t)Bn * Dn * Sn * 2);
    u16* Fb = (u16*)alloc((size_t)BSn * Dn * 2);
    u16* Pb = (u16*)alloc((size_t)Bn * Sn * Sn * 2);
    u16* Wqv1 = (u16*)alloc((size_t)512 * Dn * 2);
    u16* Wqv2 = (u16*)alloc((size_t)512 * Dn * 2);
    u16* Wfb = (u16*)alloc((size_t)Dn * Dn * 2);
    u16* Ub = (u16*)alloc((size_t)Vn * Dn * 2);

    // weight converts
    k_convert_w<<<dim3(64, 5), 256, 0, stream>>>(
        WQK1, Wqv1, WOV1, Wqv1 + (size_t)Dn * Dn, WQK2, Wqv2, WOV2,
        Wqv2 + (size_t)Dn * Dn, WF, Wfb);
    k_convert<<<(Vn * Dn) / 1024, 256, 0, stream>>>(U, Ub);

    // X = E[input] + P
    k_embed<<<BSn, 256, 0, stream>>>(inp, E, P, XfA, Xb);

    // two attention blocks
    launch_layer(XfA, XfB, Xb, Wqv1, Qb, Vt, Sc, Pb, stream);
    launch_layer(XfB, XfA, Xb, Wqv2, Qb, Vt, Sc, Pb, stream);

    // FFN residual: Fb = bf16(XfA + Xb @ Wf^T)
    k_mfma<true, false, true, false, false, false, 0>
        <<<dim3(2, 32, 1), 256, 0, stream>>>(
            Xb, Wfb, XfA, nullptr, Fb, nullptr, BSn, Dn, Dn, Dn, Dn, Dn, 1.0f,
            0, 0, 0, 0, 0);

    // logits = Fb @ Ub^T -> d_out (f32), chunked x-remap for L2
    k_mfma<false, true, false, false, false, false, 25>
        <<<dim3((Vn / 128) * (BSn / 128), 1, 1), 256, 0, stream>>>(
            Fb, Ub, nullptr, out, nullptr, nullptr, BSn, Vn, Dn, Dn, Dn, Vn,
            1.0f, 0, 0, 0, 0, BSn / 128);
}